// Round 18
// baseline (953.881 us; speedup 1.0000x reference)
//
#include <hip/hip_runtime.h>

typedef __attribute__((ext_vector_type(4))) short short4v;
typedef __attribute__((ext_vector_type(8))) short short8;
typedef __attribute__((ext_vector_type(4))) float f32x4;

#define NWIN 4096

__device__ __forceinline__ short f2bf(float f) {
    unsigned int u = __builtin_bit_cast(unsigned int, f);
    u += 0x7fffu + ((u >> 16) & 1u);
    return (short)(u >> 16);
}

// fast pack via v_perm_b32 (verified R16): round-half-up, merge high halves in ONE op.
__device__ __forceinline__ unsigned pack2h(float a, float b) {
    unsigned ua = __builtin_bit_cast(unsigned, a) + 0x8000u;
    unsigned ub = __builtin_bit_cast(unsigned, b) + 0x8000u;
    return __builtin_amdgcn_perm(ub, ua, 0x07060302u);
}

__device__ __forceinline__ short4v pk4h(float a, float b, float c, float d) {
    uint2 u;
    u.x = pack2h(a, b);
    u.y = pack2h(c, d);
    return __builtin_bit_cast(short4v, u);
}

// 16-lane-row sum via DPP row_ror (VALU-rate, no LDS pipe)
__device__ __forceinline__ float rsum16(float v) {
    int x;
    float t;
    x = __builtin_bit_cast(int, v);
    t = __builtin_bit_cast(float, __builtin_amdgcn_update_dpp(0, x, 0x128, 0xf, 0xf, true)); // ror:8
    v += t;
    x = __builtin_bit_cast(int, v);
    t = __builtin_bit_cast(float, __builtin_amdgcn_update_dpp(0, x, 0x124, 0xf, 0xf, true)); // ror:4
    v += t;
    x = __builtin_bit_cast(int, v);
    t = __builtin_bit_cast(float, __builtin_amdgcn_update_dpp(0, x, 0x122, 0xf, 0xf, true)); // ror:2
    v += t;
    x = __builtin_bit_cast(int, v);
    t = __builtin_bit_cast(float, __builtin_amdgcn_update_dpp(0, x, 0x121, 0xf, 0xf, true)); // ror:1
    v += t;
    return v;
}

#define LOG2E 1.4426950408889634f
#define QSCALE 0.17677669529663687f  // 32^-0.5

// ---- prep: transpose weights to bf16 (q-scale & log2e folded), permuted bias ----
__global__ void prep_kernel(const float* __restrict__ w_qkv,
                            const float* __restrict__ w_out,
                            const float* __restrict__ bias_table,
                            short* __restrict__ wqkvT,   // [384][128] bf16
                            short* __restrict__ woutT,   // [128][128] bf16
                            float* __restrict__ biasP)   // [4][4][64][16] f32, *log2e
{
    int id = blockIdx.x * 256 + threadIdx.x;
    if (id < 49152) {
        int j = id >> 7, k = id & 127;
        float v = w_qkv[k * 384 + j];
        if (j < 128) v *= (QSCALE * LOG2E);   // fold attention scale + log2e into Wq
        wqkvT[id] = f2bf(v);
    } else if (id < 65536) {
        int t = id - 49152;
        int j = t >> 7, k = t & 127;
        woutT[t] = f2bf(w_out[k * 128 + j]);
    } else if (id < 81920) {
        int t = id - 65536;
        // layout: [h][ib][ln][jb*4+r]; lane ln=(g<<4)|lo holds (i=16ib+lo, j=16jb+4g+r)
        int m  = t & 15;
        int ln = (t >> 4) & 63;
        int ib = (t >> 10) & 3;
        int h  = t >> 12;
        int lo = ln & 15, g = ln >> 4;
        int i = ib * 16 + lo;
        int j = (m >> 2) * 16 + g * 4 + (m & 3);
        int ri = i >> 3, ci = i & 7, rj = j >> 3, cj = j & 7;
        int idx = (ri - rj + 7) * 15 + (ci - cj + 7);
        biasP[t] = bias_table[idx * 4 + h] * LOG2E;
    }
}

// ---- fused, 8 waves/block: wave (h, token-half) does half a head's pipeline ----
__global__ __launch_bounds__(512, 4)
void attn_kernel(const float* __restrict__ x,
                 const float* __restrict__ gamma,
                 const float* __restrict__ beta,
                 const short* __restrict__ wqkvT,
                 const short* __restrict__ woutT,
                 const float* __restrict__ biasP,
                 float* __restrict__ out)
{
    // LDS map (32 KiB):
    //   [0,16K)   XN [64][128] bf16 (swz); after b2 reused as V-exchange (8 x 2K slots)
    //   [16K,32K) K-exchange (8 x 2K slots); after b3 reused as AO [64][128] bf16 (swz)
    __shared__ __align__(16) char smem[32768];

    const int tid  = threadIdx.x;
    const int w    = tid >> 6;        // wave 0..7
    const int h    = w >> 1;          // head
    const int half = w & 1;           // token half (0: tokens 0-31, 1: 32-63)
    const int ln = tid & 63;
    const int lo = ln & 15, g = ln >> 4;
    const int tb0 = half * 2;         // first of our two 16-token blocks

    const float* xwin = x + (size_t)blockIdx.x * 8192;

    // ---------------- LayerNorm: wave covers rows w*8 .. w*8+7 ----------------
    float4 va[2][2];
    #pragma unroll
    for (int p = 0; p < 2; ++p) {
        int t = w * 8 + p * 4 + g;
        const float4* xr = (const float4*)(xwin + t * 128 + lo * 8);
        va[p][0] = xr[0];
        va[p][1] = xr[1];
    }

    short8 pwk[2];
    #pragma unroll
    for (int cb = 0; cb < 2; ++cb)
        pwk[cb] = *(const short8*)(wqkvT + (128 + h * 32 + cb * 16 + lo) * 128 + g * 8);

    float4 ga0 = ((const float4*)gamma)[lo * 2], ga1 = ((const float4*)gamma)[lo * 2 + 1];
    float4 be0 = ((const float4*)beta)[lo * 2],  be1 = ((const float4*)beta)[lo * 2 + 1];

    #pragma unroll
    for (int p = 0; p < 2; ++p) {
        int t = w * 8 + p * 4 + g;
        float4 v0 = va[p][0], v1 = va[p][1];
        float s  = v0.x + v0.y + v0.z + v0.w + v1.x + v1.y + v1.z + v1.w;
        float sq = v0.x*v0.x + v0.y*v0.y + v0.z*v0.z + v0.w*v0.w
                 + v1.x*v1.x + v1.y*v1.y + v1.z*v1.z + v1.w*v1.w;
        s  = rsum16(s);
        sq = rsum16(sq);
        float mu  = s * (1.f / 128.f);
        float var = sq * (1.f / 128.f) - mu * mu;
        float rs  = rsqrtf(var + 1e-5f);
        float y0 = (v0.x - mu) * rs * ga0.x + be0.x;
        float y1 = (v0.y - mu) * rs * ga0.y + be0.y;
        float y2 = (v0.z - mu) * rs * ga0.z + be0.z;
        float y3 = (v0.w - mu) * rs * ga0.w + be0.w;
        float y4 = (v1.x - mu) * rs * ga1.x + be1.x;
        float y5 = (v1.y - mu) * rs * ga1.y + be1.y;
        float y6 = (v1.z - mu) * rs * ga1.z + be1.z;
        float y7 = (v1.w - mu) * rs * ga1.w + be1.w;
        uint4 pk;
        pk.x = pack2h(y0, y1); pk.y = pack2h(y2, y3);
        pk.z = pack2h(y4, y5); pk.w = pack2h(y6, y7);
        *(uint4*)(smem + ((t * 256 + lo * 16) ^ ((t & 7) << 4))) = pk;
    }
    __syncthreads();  // b1: XN ready

    const f32x4 z4 = {0.f, 0.f, 0.f, 0.f};

    // ---------------- QKV (own 2 token blocks only): K, Q, V passes ----------------
    short4v kA[2][4], qB[2][2], vA[2][4];
    {
        f32x4 acc[2][2];
        #pragma unroll
        for (int a = 0; a < 2; ++a) { acc[a][0] = z4; acc[a][1] = z4; }
        #pragma unroll
        for (int kk = 0; kk < 4; ++kk) {
            short8 xa[2];
            #pragma unroll
            for (int ti = 0; ti < 2; ++ti) {
                int t = (tb0 + ti) * 16 + lo;
                xa[ti] = *(const short8*)(smem + ((t * 256 + kk * 64 + g * 16) ^ ((t & 7) << 4)));
            }
            #pragma unroll
            for (int cb = 0; cb < 2; ++cb) {
                short8 wkf = (kk == 0) ? pwk[cb]
                    : *(const short8*)(wqkvT + (128 + h * 32 + cb * 16 + lo) * 128 + kk * 32 + g * 8);
                #pragma unroll
                for (int ti = 0; ti < 2; ++ti)
                    acc[cb][ti] = __builtin_amdgcn_mfma_f32_16x16x32_bf16(wkf, xa[ti], acc[cb][ti], 0, 0, 0);
            }
        }
        #pragma unroll
        for (int ck = 0; ck < 2; ++ck)
            #pragma unroll
            for (int ti = 0; ti < 2; ++ti)
                kA[ck][tb0 + ti] = pk4h(acc[ck][ti][0], acc[ck][ti][1], acc[ck][ti][2], acc[ck][ti][3]);
    }
    {
        f32x4 acc[2][2];
        #pragma unroll
        for (int a = 0; a < 2; ++a) { acc[a][0] = z4; acc[a][1] = z4; }
        #pragma unroll
        for (int kk = 0; kk < 4; ++kk) {
            short8 xa[2];
            #pragma unroll
            for (int ti = 0; ti < 2; ++ti) {
                int t = (tb0 + ti) * 16 + lo;
                xa[ti] = *(const short8*)(smem + ((t * 256 + kk * 64 + g * 16) ^ ((t & 7) << 4)));
            }
            #pragma unroll
            for (int cb = 0; cb < 2; ++cb) {
                short8 wqf = *(const short8*)(wqkvT + (h * 32 + cb * 16 + lo) * 128 + kk * 32 + g * 8);
                #pragma unroll
                for (int ti = 0; ti < 2; ++ti)
                    acc[cb][ti] = __builtin_amdgcn_mfma_f32_16x16x32_bf16(wqf, xa[ti], acc[cb][ti], 0, 0, 0);
            }
        }
        #pragma unroll
        for (int ck = 0; ck < 2; ++ck)
            #pragma unroll
            for (int ti = 0; ti < 2; ++ti)
                qB[ck][ti] = pk4h(acc[ck][ti][0], acc[ck][ti][1], acc[ck][ti][2], acc[ck][ti][3]);
    }
    {
        f32x4 acc[2][2];  // [ti][cb]
        #pragma unroll
        for (int a = 0; a < 2; ++a) { acc[a][0] = z4; acc[a][1] = z4; }
        #pragma unroll
        for (int kk = 0; kk < 4; ++kk) {
            short8 xa[2];
            #pragma unroll
            for (int ti = 0; ti < 2; ++ti) {
                int t = (tb0 + ti) * 16 + lo;
                xa[ti] = *(const short8*)(smem + ((t * 256 + kk * 64 + g * 16) ^ ((t & 7) << 4)));
            }
            #pragma unroll
            for (int cb = 0; cb < 2; ++cb) {
                short8 wvf = *(const short8*)(wqkvT + (256 + h * 32 + cb * 16 + lo) * 128 + kk * 32 + g * 8);
                #pragma unroll
                for (int ti = 0; ti < 2; ++ti)
                    acc[ti][cb] = __builtin_amdgcn_mfma_f32_16x16x32_bf16(xa[ti], wvf, acc[ti][cb], 0, 0, 0);
            }
        }
        #pragma unroll
        for (int cb = 0; cb < 2; ++cb)
            #pragma unroll
            for (int ti = 0; ti < 2; ++ti)
                vA[cb][tb0 + ti] = pk4h(acc[ti][cb][0], acc[ti][cb][1], acc[ti][cb][2], acc[ti][cb][3]);
    }

    // ---------------- K exchange: own K -> [16K,32K) slot w ----------------
    {
        char* kown = smem + 16384 + w * 2048;
        #pragma unroll
        for (int ck = 0; ck < 2; ++ck)
            #pragma unroll
            for (int ti = 0; ti < 2; ++ti)
                *(uint2*)(kown + (ck * 2 + ti) * 512 + ln * 8) =
                    __builtin_bit_cast(uint2, kA[ck][tb0 + ti]);
    }
    __syncthreads();  // b2: all XN reads done + K visible

    {
        char* kpart = smem + 16384 + (w ^ 1) * 2048;
        int pb0 = 2 - tb0;
        #pragma unroll
        for (int ck = 0; ck < 2; ++ck)
            #pragma unroll
            for (int ti = 0; ti < 2; ++ti)
                kA[ck][pb0 + ti] = __builtin_bit_cast(short4v,
                    *(const uint2*)(kpart + (ck * 2 + ti) * 512 + ln * 8));
    }
    // V exchange: own V -> [0,16K) (XN dead) slot w
    {
        char* vown = smem + w * 2048;
        #pragma unroll
        for (int cb = 0; cb < 2; ++cb)
            #pragma unroll
            for (int ti = 0; ti < 2; ++ti)
                *(uint2*)(vown + (cb * 2 + ti) * 512 + ln * 8) =
                    __builtin_bit_cast(uint2, vA[cb][tb0 + ti]);
    }
    __syncthreads();  // b3: K reads done (pre-b3) + V visible

    {
        char* vpart = smem + (w ^ 1) * 2048;
        int pb0 = 2 - tb0;
        #pragma unroll
        for (int cb = 0; cb < 2; ++cb)
            #pragma unroll
            for (int ti = 0; ti < 2; ++ti)
                vA[cb][pb0 + ti] = __builtin_bit_cast(short4v,
                    *(const uint2*)(vpart + (cb * 2 + ti) * 512 + ln * 8));
    }

    // ---------------- attn: 2 query blocks (ib = tb0, tb0+1) ----------------
    f32x4 ot[2][2];  // [cb][ti]
    #pragma unroll
    for (int a = 0; a < 2; ++a) { ot[a][0] = z4; ot[a][1] = z4; }

    float inv[2];
    #pragma unroll
    for (int ti = 0; ti < 2; ++ti) {
        int ib = tb0 + ti;
        const f32x4* bp = (const f32x4*)(biasP + ((h * 4 + ib) * 64 + ln) * 16);
        f32x4 st[4];
        #pragma unroll
        for (int jb = 0; jb < 4; ++jb) st[jb] = bp[jb];
        __builtin_amdgcn_s_setprio(1);
        #pragma unroll
        for (int jb = 0; jb < 4; ++jb) {
            st[jb] = __builtin_amdgcn_mfma_f32_16x16x16bf16_1k(kA[0][jb], qB[0][ti], st[jb], 0, 0, 0);
            st[jb] = __builtin_amdgcn_mfma_f32_16x16x16bf16_1k(kA[1][jb], qB[1][ti], st[jb], 0, 0, 0);
        }
        __builtin_amdgcn_s_setprio(0);

        float s = 0.f;
        short4v pB[4];
        #pragma unroll
        for (int jb = 0; jb < 4; ++jb) {
            float e0 = __builtin_exp2f(st[jb][0]);
            float e1 = __builtin_exp2f(st[jb][1]);
            float e2 = __builtin_exp2f(st[jb][2]);
            float e3 = __builtin_exp2f(st[jb][3]);
            s += (e0 + e1) + (e2 + e3);
            pB[jb] = pk4h(e0, e1, e2, e3);
        }
        s += __shfl_xor(s, 16, 64);
        s += __shfl_xor(s, 32, 64);
        inv[ti] = 1.f / s;

        __builtin_amdgcn_s_setprio(1);
        #pragma unroll
        for (int jk = 0; jk < 4; ++jk)
            #pragma unroll
            for (int cb = 0; cb < 2; ++cb)
                ot[cb][ti] = __builtin_amdgcn_mfma_f32_16x16x16bf16_1k(vA[cb][jk], pB[jk], ot[cb][ti], 0, 0, 0);
        __builtin_amdgcn_s_setprio(0);
    }

    // ---------------- AO writes into [16K,32K) (K buffer dead since b3) ----------------
    char* aob = smem + 16384;
    #pragma unroll
    for (int cb = 0; cb < 2; ++cb)
        #pragma unroll
        for (int ti = 0; ti < 2; ++ti) {
            int i = (tb0 + ti) * 16 + lo;
            float sc = inv[ti];
            uint2 wv;
            wv.x = pack2h(ot[cb][ti][0] * sc, ot[cb][ti][1] * sc);
            wv.y = pack2h(ot[cb][ti][2] * sc, ot[cb][ti][3] * sc);
            *(uint2*)(aob + ((i * 256 + (h * 32 + cb * 16 + g * 4) * 2) ^ ((i & 7) << 4))) = wv;
        }

    short8 wof_c[2];
    #pragma unroll
    for (int cj = 0; cj < 2; ++cj)
        wof_c[cj] = *(const short8*)(woutT + (h * 32 + cj * 16 + lo) * 128 + g * 8);

    __syncthreads();  // b4: AO ready

    // ---------------- out projection (own 2 token blocks) ----------------
    f32x4 ft[2][2];  // [cj][ti]
    #pragma unroll
    for (int a = 0; a < 2; ++a) { ft[a][0] = z4; ft[a][1] = z4; }

    #pragma unroll
    for (int kk = 0; kk < 4; ++kk) {
        short8 ao[2];
        #pragma unroll
        for (int ti = 0; ti < 2; ++ti) {
            int t = (tb0 + ti) * 16 + lo;
            ao[ti] = *(const short8*)(aob + ((t * 256 + kk * 64 + g * 16) ^ ((t & 7) << 4)));
        }
        __builtin_amdgcn_s_setprio(1);
        #pragma unroll
        for (int cj = 0; cj < 2; ++cj) {
            short8 wof = (kk == 0) ? wof_c[cj]
                : *(const short8*)(woutT + (h * 32 + cj * 16 + lo) * 128 + kk * 32 + g * 8);
            #pragma unroll
            for (int ti = 0; ti < 2; ++ti)
                ft[cj][ti] = __builtin_amdgcn_mfma_f32_16x16x32_bf16(wof, ao[ti], ft[cj][ti], 0, 0, 0);
        }
        __builtin_amdgcn_s_setprio(0);
    }

    float* owin = out + (size_t)blockIdx.x * 8192;
    #pragma unroll
    for (int cj = 0; cj < 2; ++cj)
        #pragma unroll
        for (int ti = 0; ti < 2; ++ti) {
            int t = (tb0 + ti) * 16 + lo;
            *(f32x4*)(owin + t * 128 + h * 32 + cj * 16 + g * 4) = ft[cj][ti];
        }
}

extern "C" void kernel_launch(void* const* d_in, const int* in_sizes, int n_in,
                              void* d_out, int out_size, void* d_ws, size_t ws_size,
                              hipStream_t stream) {
    const float* x          = (const float*)d_in[0];
    const float* gamma      = (const float*)d_in[1];
    const float* beta       = (const float*)d_in[2];
    const float* w_qkv      = (const float*)d_in[3];
    const float* w_out      = (const float*)d_in[4];
    const float* bias_table = (const float*)d_in[5];

    short* wqkvT = (short*)d_ws;                    // 98304 B
    short* woutT = (short*)((char*)d_ws + 98304);   // 32768 B
    float* biasP = (float*)((char*)d_ws + 131072);  // 65536 B

    prep_kernel<<<320, 256, 0, stream>>>(w_qkv, w_out, bias_table, wqkvT, woutT, biasP);
    attn_kernel<<<NWIN, 512, 0, stream>>>(x, gamma, beta, wqkvT, woutT, biasP, (float*)d_out);
}